// Round 11
// baseline (50.312 us; speedup 1.0000x reference)
//
#include <hip/hip_runtime.h>

// QCQP quaternion loss. Per element: smallest eigenpair of 4x4 symmetric A
// via characteristic polynomial + monotone Newton from Gershgorin lower
// bound; eigenvector = 4D cross of 3 rows of A-lam*I (max-norm candidate);
// loss = 8(1 - <v,qt>^2/|v|^2). Mean-reduce.
//
// R10: R9 (21.4us) minus two costs:
// (a) reduce kernel (1-block dispatch ~3us) -> 8B memset node + R8-style
//     fused atomic finalize in the main kernel (last block writes out).
// (b) Newton 12 -> 8 iterations (absmax was 0.0 with huge threshold slack;
//     monotone-from-below so early exit degrades gracefully).
// Pinned-asm pipeline from R8/R9 unchanged (PAIRS=2, vmcnt(7)/vmcnt(0)).

#define TPB 256
#define PAIRS 2

typedef float vf4 __attribute__((ext_vector_type(4)));

struct Pair { vf4 f0, f1, f2, f3, f4, q0, q1; };

__device__ __forceinline__ void issue_loads(const float* a, const float* q,
                                            Pair& d) {
    unsigned long long aa = (unsigned long long)a;
    unsigned long long qq = (unsigned long long)q;
    asm volatile("global_load_dwordx4 %0, %1, off"           : "=v"(d.f0) : "v"(aa));
    asm volatile("global_load_dwordx4 %0, %1, off offset:16" : "=v"(d.f1) : "v"(aa));
    asm volatile("global_load_dwordx4 %0, %1, off offset:32" : "=v"(d.f2) : "v"(aa));
    asm volatile("global_load_dwordx4 %0, %1, off offset:48" : "=v"(d.f3) : "v"(aa));
    asm volatile("global_load_dwordx4 %0, %1, off offset:64" : "=v"(d.f4) : "v"(aa));
    asm volatile("global_load_dwordx4 %0, %1, off"           : "=v"(d.q0) : "v"(qq));
    asm volatile("global_load_dwordx4 %0, %1, off offset:16" : "=v"(d.q1) : "v"(qq));
}

__device__ __forceinline__ void cross4(const float* x, const float* y,
                                       const float* z, float* w) {
    float m01 = y[0]*z[1] - y[1]*z[0];
    float m02 = y[0]*z[2] - y[2]*z[0];
    float m03 = y[0]*z[3] - y[3]*z[0];
    float m12 = y[1]*z[2] - y[2]*z[1];
    float m13 = y[1]*z[3] - y[3]*z[1];
    float m23 = y[2]*z[3] - y[3]*z[2];
    w[0] =  (x[1]*m23 - x[2]*m13 + x[3]*m12);
    w[1] = -(x[0]*m23 - x[2]*m03 + x[3]*m02);
    w[2] =  (x[0]*m13 - x[1]*m03 + x[3]*m01);
    w[3] = -(x[0]*m12 - x[1]*m02 + x[2]*m01);
}

__device__ __forceinline__ float det3s(float p, float q, float r,
                                       float s, float t, float u) {
    return p*(s*u - t*t) - q*(q*u - r*t) + r*(q*t - r*s);
}

// ---- per-element solve: R1's verified path, Newton trimmed to 8 iters ----
__device__ __forceinline__ float solve_elem(const float a[10], float4 qt) {
    float m00 = -a[0], m01 = -a[1], m02 = -a[2], m03 = -a[3];
    float m11 = -a[4], m12 = -a[5], m13 = -a[6];
    float m22 = -a[7], m23 = -a[8], m33 = -a[9];

    float e1 = m00 + m11 + m22 + m33;
    float e2 = m00*m11 - m01*m01 + m00*m22 - m02*m02 + m00*m33 - m03*m03
             + m11*m22 - m12*m12 + m11*m33 - m13*m13 + m22*m33 - m23*m23;
    float e3 = det3s(m11, m12, m13, m22, m23, m33)
             + det3s(m00, m02, m03, m22, m23, m33)
             + det3s(m00, m01, m03, m11, m13, m33)
             + det3s(m00, m01, m02, m11, m12, m22);
    float r1v[4] = {m01, m11, m12, m13};
    float r2v[4] = {m02, m12, m22, m23};
    float r3v[4] = {m03, m13, m23, m33};
    float cw[4];
    cross4(r1v, r2v, r3v, cw);
    float e4 = m00*cw[0] + m01*cw[1] + m02*cw[2] + m03*cw[3];

    float s0 = fabsf(m01) + fabsf(m02) + fabsf(m03);
    float s1 = fabsf(m01) + fabsf(m12) + fabsf(m13);
    float s2 = fabsf(m02) + fabsf(m12) + fabsf(m23);
    float s3 = fabsf(m03) + fabsf(m13) + fabsf(m23);
    float lo = fminf(fminf(m00 - s0, m11 - s1), fminf(m22 - s2, m33 - s3)) - 1e-3f;
    float hi = fminf(fminf(m00, m11), fminf(m22, m33));
    float lam = lo;
    #pragma unroll
    for (int it = 0; it < 8; ++it) {
        float p  = (((lam - e1)*lam + e2)*lam - e3)*lam + e4;
        float dp = ((4.f*lam - 3.f*e1)*lam + 2.f*e2)*lam - e3;
        dp = fminf(dp, -1e-12f);
        lam = lam - p * __builtin_amdgcn_rcpf(dp);
        lam = fminf(fmaxf(lam, lo), hi);
    }

    float R0[4] = {m00 - lam, m01, m02, m03};
    float R1[4] = {m01, m11 - lam, m12, m13};
    float R2[4] = {m02, m12, m22 - lam, m23};
    float R3[4] = {m03, m13, m23, m33 - lam};
    float c0[4], c1[4], c2[4], c3[4];
    cross4(R1, R2, R3, c0);
    cross4(R0, R2, R3, c1);
    cross4(R0, R1, R3, c2);
    cross4(R0, R1, R2, c3);
    float n0 = c0[0]*c0[0] + c0[1]*c0[1] + c0[2]*c0[2] + c0[3]*c0[3];
    float n1 = c1[0]*c1[0] + c1[1]*c1[1] + c1[2]*c1[2] + c1[3]*c1[3];
    float n2 = c2[0]*c2[0] + c2[1]*c2[1] + c2[2]*c2[2] + c2[3]*c2[3];
    float n3 = c3[0]*c3[0] + c3[1]*c3[1] + c3[2]*c3[2] + c3[3]*c3[3];

    float bn = n0, w0 = c0[0], w1 = c0[1], w2 = c0[2], w3 = c0[3];
    bool b;
    b = n1 > bn; bn = b ? n1 : bn; w0 = b ? c1[0] : w0; w1 = b ? c1[1] : w1;
                 w2 = b ? c1[2] : w2; w3 = b ? c1[3] : w3;
    b = n2 > bn; bn = b ? n2 : bn; w0 = b ? c2[0] : w0; w1 = b ? c2[1] : w1;
                 w2 = b ? c2[2] : w2; w3 = b ? c2[3] : w3;
    b = n3 > bn; bn = b ? n3 : bn; w0 = b ? c3[0] : w0; w1 = b ? c3[1] : w1;
                 w2 = b ? c3[2] : w2; w3 = b ? c3[3] : w3;

    float d = w0*qt.x + w1*qt.y + w2*qt.z + w3*qt.w;
    float inv = __builtin_amdgcn_rcpf(fmaxf(bn, 1e-20f));
    float loss = 8.f * (bn - d*d) * inv;
    return fminf(fmaxf(loss, 0.f), 8.f);
}

// DPP wave64 sum step: VALU pipe only. ctrl/mask are compile-time consts.
template <int CTRL, int ROW_MASK>
__device__ __forceinline__ float dpp_add(float v) {
    int t = __builtin_amdgcn_update_dpp(0, __builtin_bit_cast(int, v),
                                        CTRL, ROW_MASK, 0xf, true);
    return v + __builtin_bit_cast(float, t);
}

__device__ __forceinline__ float wave_sum(float v) {
    v = dpp_add<0x111, 0xf>(v);   // row_shr:1
    v = dpp_add<0x112, 0xf>(v);   // row_shr:2
    v = dpp_add<0x114, 0xf>(v);   // row_shr:4
    v = dpp_add<0x118, 0xf>(v);   // row_shr:8
    v = dpp_add<0x142, 0xa>(v);   // row_bcast:15 -> rows 1,3
    v = dpp_add<0x143, 0xc>(v);   // row_bcast:31 -> rows 2,3
    return __builtin_bit_cast(float,
        __builtin_amdgcn_readlane(__builtin_bit_cast(int, v), 63));
}

__global__ __launch_bounds__(TPB) void qcqp_loss_kernel(
    const float* __restrict__ A_vec, const float* __restrict__ q_t,
    float* __restrict__ acc, unsigned int* __restrict__ cnt,
    float* __restrict__ out, int B, int T, int nblocks)
{
    int t = blockIdx.x * blockDim.x + threadIdx.x;
    int Ptot = B >> 1;                       // whole pairs
    float lsum = 0.f;

    Pair Pd, Nd;
    int curp = t;
    {
        int c = (curp < Ptot) ? curp : 0;
        issue_loads(A_vec + (size_t)c * 20, q_t + (size_t)c * 8, Pd);
    }
    int nxtp = curp;

    #define STEP(K, VMSTR)                                                    \
    {                                                                         \
        if ((K) + 1 < PAIRS) {                                                \
            nxtp = t + ((K) + 1) * T;                                         \
            int nc = (nxtp < Ptot) ? nxtp : 0;                                \
            issue_loads(A_vec + (size_t)nc * 20, q_t + (size_t)nc * 8, Nd);   \
        }                                                                     \
        asm volatile("s_waitcnt vmcnt(" VMSTR ")" ::: "memory");              \
        __builtin_amdgcn_sched_barrier(0);                                    \
        {                                                                     \
            bool ok = (curp < Ptot);                                          \
            float a0[10] = {Pd.f0.x, Pd.f0.y, Pd.f0.z, Pd.f0.w,               \
                            Pd.f1.x, Pd.f1.y, Pd.f1.z, Pd.f1.w,               \
                            Pd.f2.x, Pd.f2.y};                                \
            float a1[10] = {Pd.f2.z, Pd.f2.w, Pd.f3.x, Pd.f3.y,               \
                            Pd.f3.z, Pd.f3.w, Pd.f4.x, Pd.f4.y,               \
                            Pd.f4.z, Pd.f4.w};                                \
            float4 qt0 = make_float4(Pd.q0.x, Pd.q0.y, Pd.q0.z, Pd.q0.w);     \
            float4 qt1 = make_float4(Pd.q1.x, Pd.q1.y, Pd.q1.z, Pd.q1.w);     \
            float L0 = solve_elem(a0, qt0);                                   \
            float L1 = solve_elem(a1, qt1);                                   \
            lsum += ok ? (L0 + L1) : 0.f;                                     \
        }                                                                     \
        Pd = Nd; curp = nxtp;                                                 \
    }

    STEP(0, "7")
    STEP(1, "0")
    #undef STEP

    float wsum = wave_sum(lsum);

    __shared__ float sm[TPB / 64];
    int lane = threadIdx.x & 63, wid = threadIdx.x >> 6;
    if (lane == 0) sm[wid] = wsum;
    __syncthreads();
    if (threadIdx.x == 0) {
        atomicAdd(acc, sm[0] + sm[1] + sm[2] + sm[3]);
        __threadfence();
        unsigned int c = atomicAdd(cnt, 1u);
        if (c == (unsigned int)(nblocks - 1)) {
            float total = atomicAdd(acc, 0.f);   // all block adds visible
            if (B & 1) {   // odd-B tail element (not hit for B=2^20)
                const float* av = A_vec + (size_t)(B - 1) * 10;
                float2 v01 = *(const float2*)(av + 0);
                float2 v23 = *(const float2*)(av + 2);
                float2 v45 = *(const float2*)(av + 4);
                float2 v67 = *(const float2*)(av + 6);
                float2 v89 = *(const float2*)(av + 8);
                float a0[10] = {v01.x, v01.y, v23.x, v23.y, v45.x,
                                v45.y, v67.x, v67.y, v89.x, v89.y};
                float4 qt0 = *(const float4*)(q_t + (size_t)(B - 1) * 4);
                total += solve_elem(a0, qt0);
            }
            out[0] = total / (float)B;
        }
    }
}

extern "C" void kernel_launch(void* const* d_in, const int* in_sizes, int n_in,
                              void* d_out, int out_size, void* d_ws, size_t ws_size,
                              hipStream_t stream)
{
    const float* A_vec = (const float*)d_in[0];
    const float* q_t   = (const float*)d_in[1];
    int B = in_sizes[0] / 10;
    float* acc = (float*)d_ws;
    unsigned int* cnt = (unsigned int*)((char*)d_ws + sizeof(float));

    (void)hipMemsetAsync(d_ws, 0, 2 * sizeof(float), stream);
    int Ptot = B >> 1;
    int nblocks = (Ptot + TPB * PAIRS - 1) / (TPB * PAIRS);
    int T = nblocks * TPB;                  // thread count; pair idx = t + k*T
    qcqp_loss_kernel<<<nblocks, TPB, 0, stream>>>(
        A_vec, q_t, acc, cnt, (float*)d_out, B, T, nblocks);
}

// Round 12
// 19.809 us; speedup vs baseline: 2.5399x; 2.5399x over previous
//
#include <hip/hip_runtime.h>

// QCQP quaternion loss. Per element: smallest eigenpair of 4x4 symmetric A
// via characteristic polynomial + monotone Newton from Gershgorin lower
// bound; eigenvector = 4D cross of 3 rows of A-lam*I (max-norm candidate);
// loss = 8(1 - <v,qt>^2/|v|^2). Mean-reduce.
//
// R11 = R9 (21.4us, proven) + ONLY Newton 12->8. R10's fused atomic
// finalize (atomicAdd + __threadfence + counter on one cacheline x1024
// blocks across 8 XCDs) cost ~30us -- reverted to plain-store partials +
// tiny reduce kernel. Pinned-asm pipeline unchanged (PAIRS=2, vmcnt(7)/0).

#define TPB 256
#define PAIRS 2

typedef float vf4 __attribute__((ext_vector_type(4)));

struct Pair { vf4 f0, f1, f2, f3, f4, q0, q1; };

__device__ __forceinline__ void issue_loads(const float* a, const float* q,
                                            Pair& d) {
    unsigned long long aa = (unsigned long long)a;
    unsigned long long qq = (unsigned long long)q;
    asm volatile("global_load_dwordx4 %0, %1, off"           : "=v"(d.f0) : "v"(aa));
    asm volatile("global_load_dwordx4 %0, %1, off offset:16" : "=v"(d.f1) : "v"(aa));
    asm volatile("global_load_dwordx4 %0, %1, off offset:32" : "=v"(d.f2) : "v"(aa));
    asm volatile("global_load_dwordx4 %0, %1, off offset:48" : "=v"(d.f3) : "v"(aa));
    asm volatile("global_load_dwordx4 %0, %1, off offset:64" : "=v"(d.f4) : "v"(aa));
    asm volatile("global_load_dwordx4 %0, %1, off"           : "=v"(d.q0) : "v"(qq));
    asm volatile("global_load_dwordx4 %0, %1, off offset:16" : "=v"(d.q1) : "v"(qq));
}

__device__ __forceinline__ void cross4(const float* x, const float* y,
                                       const float* z, float* w) {
    float m01 = y[0]*z[1] - y[1]*z[0];
    float m02 = y[0]*z[2] - y[2]*z[0];
    float m03 = y[0]*z[3] - y[3]*z[0];
    float m12 = y[1]*z[2] - y[2]*z[1];
    float m13 = y[1]*z[3] - y[3]*z[1];
    float m23 = y[2]*z[3] - y[3]*z[2];
    w[0] =  (x[1]*m23 - x[2]*m13 + x[3]*m12);
    w[1] = -(x[0]*m23 - x[2]*m03 + x[3]*m02);
    w[2] =  (x[0]*m13 - x[1]*m03 + x[3]*m01);
    w[3] = -(x[0]*m12 - x[1]*m02 + x[2]*m01);
}

__device__ __forceinline__ float det3s(float p, float q, float r,
                                       float s, float t, float u) {
    return p*(s*u - t*t) - q*(q*u - r*t) + r*(q*t - r*s);
}

// ---- per-element solve: R1's verified path, Newton trimmed to 8 iters ----
__device__ __forceinline__ float solve_elem(const float a[10], float4 qt) {
    float m00 = -a[0], m01 = -a[1], m02 = -a[2], m03 = -a[3];
    float m11 = -a[4], m12 = -a[5], m13 = -a[6];
    float m22 = -a[7], m23 = -a[8], m33 = -a[9];

    float e1 = m00 + m11 + m22 + m33;
    float e2 = m00*m11 - m01*m01 + m00*m22 - m02*m02 + m00*m33 - m03*m03
             + m11*m22 - m12*m12 + m11*m33 - m13*m13 + m22*m33 - m23*m23;
    float e3 = det3s(m11, m12, m13, m22, m23, m33)
             + det3s(m00, m02, m03, m22, m23, m33)
             + det3s(m00, m01, m03, m11, m13, m33)
             + det3s(m00, m01, m02, m11, m12, m22);
    float r1v[4] = {m01, m11, m12, m13};
    float r2v[4] = {m02, m12, m22, m23};
    float r3v[4] = {m03, m13, m23, m33};
    float cw[4];
    cross4(r1v, r2v, r3v, cw);
    float e4 = m00*cw[0] + m01*cw[1] + m02*cw[2] + m03*cw[3];

    float s0 = fabsf(m01) + fabsf(m02) + fabsf(m03);
    float s1 = fabsf(m01) + fabsf(m12) + fabsf(m13);
    float s2 = fabsf(m02) + fabsf(m12) + fabsf(m23);
    float s3 = fabsf(m03) + fabsf(m13) + fabsf(m23);
    float lo = fminf(fminf(m00 - s0, m11 - s1), fminf(m22 - s2, m33 - s3)) - 1e-3f;
    float hi = fminf(fminf(m00, m11), fminf(m22, m33));
    float lam = lo;
    #pragma unroll
    for (int it = 0; it < 8; ++it) {
        float p  = (((lam - e1)*lam + e2)*lam - e3)*lam + e4;
        float dp = ((4.f*lam - 3.f*e1)*lam + 2.f*e2)*lam - e3;
        dp = fminf(dp, -1e-12f);
        lam = lam - p * __builtin_amdgcn_rcpf(dp);
        lam = fminf(fmaxf(lam, lo), hi);
    }

    float R0[4] = {m00 - lam, m01, m02, m03};
    float R1[4] = {m01, m11 - lam, m12, m13};
    float R2[4] = {m02, m12, m22 - lam, m23};
    float R3[4] = {m03, m13, m23, m33 - lam};
    float c0[4], c1[4], c2[4], c3[4];
    cross4(R1, R2, R3, c0);
    cross4(R0, R2, R3, c1);
    cross4(R0, R1, R3, c2);
    cross4(R0, R1, R2, c3);
    float n0 = c0[0]*c0[0] + c0[1]*c0[1] + c0[2]*c0[2] + c0[3]*c0[3];
    float n1 = c1[0]*c1[0] + c1[1]*c1[1] + c1[2]*c1[2] + c1[3]*c1[3];
    float n2 = c2[0]*c2[0] + c2[1]*c2[1] + c2[2]*c2[2] + c2[3]*c2[3];
    float n3 = c3[0]*c3[0] + c3[1]*c3[1] + c3[2]*c3[2] + c3[3]*c3[3];

    float bn = n0, w0 = c0[0], w1 = c0[1], w2 = c0[2], w3 = c0[3];
    bool b;
    b = n1 > bn; bn = b ? n1 : bn; w0 = b ? c1[0] : w0; w1 = b ? c1[1] : w1;
                 w2 = b ? c1[2] : w2; w3 = b ? c1[3] : w3;
    b = n2 > bn; bn = b ? n2 : bn; w0 = b ? c2[0] : w0; w1 = b ? c2[1] : w1;
                 w2 = b ? c2[2] : w2; w3 = b ? c2[3] : w3;
    b = n3 > bn; bn = b ? n3 : bn; w0 = b ? c3[0] : w0; w1 = b ? c3[1] : w1;
                 w2 = b ? c3[2] : w2; w3 = b ? c3[3] : w3;

    float d = w0*qt.x + w1*qt.y + w2*qt.z + w3*qt.w;
    float inv = __builtin_amdgcn_rcpf(fmaxf(bn, 1e-20f));
    float loss = 8.f * (bn - d*d) * inv;
    return fminf(fmaxf(loss, 0.f), 8.f);
}

// DPP wave64 sum step: VALU pipe only. ctrl/mask are compile-time consts.
template <int CTRL, int ROW_MASK>
__device__ __forceinline__ float dpp_add(float v) {
    int t = __builtin_amdgcn_update_dpp(0, __builtin_bit_cast(int, v),
                                        CTRL, ROW_MASK, 0xf, true);
    return v + __builtin_bit_cast(float, t);
}

__device__ __forceinline__ float wave_sum(float v) {
    v = dpp_add<0x111, 0xf>(v);   // row_shr:1
    v = dpp_add<0x112, 0xf>(v);   // row_shr:2
    v = dpp_add<0x114, 0xf>(v);   // row_shr:4
    v = dpp_add<0x118, 0xf>(v);   // row_shr:8
    v = dpp_add<0x142, 0xa>(v);   // row_bcast:15 -> rows 1,3
    v = dpp_add<0x143, 0xc>(v);   // row_bcast:31 -> rows 2,3
    return __builtin_bit_cast(float,
        __builtin_amdgcn_readlane(__builtin_bit_cast(int, v), 63));
}

__global__ __launch_bounds__(TPB) void qcqp_loss_kernel(
    const float* __restrict__ A_vec, const float* __restrict__ q_t,
    float* __restrict__ part, int B, int T)
{
    int t = blockIdx.x * blockDim.x + threadIdx.x;
    int Ptot = B >> 1;                       // whole pairs
    float lsum = 0.f;

    Pair Pd, Nd;
    int curp = t;
    {
        int c = (curp < Ptot) ? curp : 0;
        issue_loads(A_vec + (size_t)c * 20, q_t + (size_t)c * 8, Pd);
    }
    int nxtp = curp;

    #define STEP(K, VMSTR)                                                    \
    {                                                                         \
        if ((K) + 1 < PAIRS) {                                                \
            nxtp = t + ((K) + 1) * T;                                         \
            int nc = (nxtp < Ptot) ? nxtp : 0;                                \
            issue_loads(A_vec + (size_t)nc * 20, q_t + (size_t)nc * 8, Nd);   \
        }                                                                     \
        asm volatile("s_waitcnt vmcnt(" VMSTR ")" ::: "memory");              \
        __builtin_amdgcn_sched_barrier(0);                                    \
        {                                                                     \
            bool ok = (curp < Ptot);                                          \
            float a0[10] = {Pd.f0.x, Pd.f0.y, Pd.f0.z, Pd.f0.w,               \
                            Pd.f1.x, Pd.f1.y, Pd.f1.z, Pd.f1.w,               \
                            Pd.f2.x, Pd.f2.y};                                \
            float a1[10] = {Pd.f2.z, Pd.f2.w, Pd.f3.x, Pd.f3.y,               \
                            Pd.f3.z, Pd.f3.w, Pd.f4.x, Pd.f4.y,               \
                            Pd.f4.z, Pd.f4.w};                                \
            float4 qt0 = make_float4(Pd.q0.x, Pd.q0.y, Pd.q0.z, Pd.q0.w);     \
            float4 qt1 = make_float4(Pd.q1.x, Pd.q1.y, Pd.q1.z, Pd.q1.w);     \
            float L0 = solve_elem(a0, qt0);                                   \
            float L1 = solve_elem(a1, qt1);                                   \
            lsum += ok ? (L0 + L1) : 0.f;                                     \
        }                                                                     \
        Pd = Nd; curp = nxtp;                                                 \
    }

    STEP(0, "7")
    STEP(1, "0")
    #undef STEP

    float wsum = wave_sum(lsum);

    __shared__ float sm[TPB / 64];
    int lane = threadIdx.x & 63, wid = threadIdx.x >> 6;
    if (lane == 0) sm[wid] = wsum;
    __syncthreads();
    if (threadIdx.x == 0)
        part[blockIdx.x] = sm[0] + sm[1] + sm[2] + sm[3];   // plain store
}

__global__ __launch_bounds__(TPB) void qcqp_reduce_kernel(
    const float* __restrict__ part, const float* __restrict__ A_vec,
    const float* __restrict__ q_t, float* __restrict__ out,
    int nparts, int B)
{
    float s = 0.f;
    for (int i = threadIdx.x; i < nparts; i += TPB)
        s += part[i];
    float wsum = wave_sum(s);

    __shared__ float sm[TPB / 64];
    int lane = threadIdx.x & 63, wid = threadIdx.x >> 6;
    if (lane == 0) sm[wid] = wsum;
    __syncthreads();
    if (threadIdx.x == 0) {
        float total = sm[0] + sm[1] + sm[2] + sm[3];
        if (B & 1) {   // odd-B tail element (not hit for B=2^20)
            const float* av = A_vec + (size_t)(B - 1) * 10;
            float2 v01 = *(const float2*)(av + 0);
            float2 v23 = *(const float2*)(av + 2);
            float2 v45 = *(const float2*)(av + 4);
            float2 v67 = *(const float2*)(av + 6);
            float2 v89 = *(const float2*)(av + 8);
            float a0[10] = {v01.x, v01.y, v23.x, v23.y, v45.x,
                            v45.y, v67.x, v67.y, v89.x, v89.y};
            float4 qt0 = *(const float4*)(q_t + (size_t)(B - 1) * 4);
            total += solve_elem(a0, qt0);
        }
        out[0] = total / (float)B;
    }
}

extern "C" void kernel_launch(void* const* d_in, const int* in_sizes, int n_in,
                              void* d_out, int out_size, void* d_ws, size_t ws_size,
                              hipStream_t stream)
{
    const float* A_vec = (const float*)d_in[0];
    const float* q_t   = (const float*)d_in[1];
    int B = in_sizes[0] / 10;
    float* part = (float*)d_ws;

    int Ptot = B >> 1;
    int nblocks = (Ptot + TPB * PAIRS - 1) / (TPB * PAIRS);
    int T = nblocks * TPB;                  // thread count; pair idx = t + k*T
    qcqp_loss_kernel<<<nblocks, TPB, 0, stream>>>(A_vec, q_t, part, B, T);
    qcqp_reduce_kernel<<<1, TPB, 0, stream>>>(part, A_vec, q_t,
                                              (float*)d_out, nblocks, B);
}

// Round 13
// 18.550 us; speedup vs baseline: 2.7123x; 1.0679x over previous
//
#include <hip/hip_runtime.h>

// QCQP quaternion loss. Per element: smallest eigenpair of 4x4 symmetric A
// via characteristic polynomial + monotone Newton from Gershgorin lower
// bound; eigenvector via rank-1 adjugate: adj(A - lam I) = k v v^T, so
// adj*ones ~ v. adj*ones = comb(R1-R0, minors(R2,R3)) + comb(R3-R2,
// minors(R0,R1)) -- 12 shared 2x2 minors + 2 combinations (~76 ops vs
// ~180 for 4 cross4 + max-norm select). Signs: N0=+col0, N1=-col1,
// N2=+col2, N3=-col3 (derived + checked on diagonal case).
// Loss = 8(1 - <w,qt>^2/|w|^2). Mean-reduce: plain-store partials + tiny
// reduce kernel (R10 showed atomic finalize costs ~30us at 1k blocks).
// R12 = R11 structure (pinned-asm PAIRS=2 pipeline) + adjugate-sum solve.

#define TPB 256
#define PAIRS 2

typedef float vf4 __attribute__((ext_vector_type(4)));

struct Pair { vf4 f0, f1, f2, f3, f4, q0, q1; };

__device__ __forceinline__ void issue_loads(const float* a, const float* q,
                                            Pair& d) {
    unsigned long long aa = (unsigned long long)a;
    unsigned long long qq = (unsigned long long)q;
    asm volatile("global_load_dwordx4 %0, %1, off"           : "=v"(d.f0) : "v"(aa));
    asm volatile("global_load_dwordx4 %0, %1, off offset:16" : "=v"(d.f1) : "v"(aa));
    asm volatile("global_load_dwordx4 %0, %1, off offset:32" : "=v"(d.f2) : "v"(aa));
    asm volatile("global_load_dwordx4 %0, %1, off offset:48" : "=v"(d.f3) : "v"(aa));
    asm volatile("global_load_dwordx4 %0, %1, off offset:64" : "=v"(d.f4) : "v"(aa));
    asm volatile("global_load_dwordx4 %0, %1, off"           : "=v"(d.q0) : "v"(qq));
    asm volatile("global_load_dwordx4 %0, %1, off offset:16" : "=v"(d.q1) : "v"(qq));
}

__device__ __forceinline__ float det3s(float p, float q, float r,
                                       float s, float t, float u) {
    return p*(s*u - t*t) - q*(q*u - r*t) + r*(q*t - r*s);
}

// comb(y, m): expansion of the generalized cross with precomputed 2x2
// minors m_ij of the other two rows (matches cross4's internal layout).
__device__ __forceinline__ void comb4(const float y[4],
                                      float m01, float m02, float m03,
                                      float m12, float m13, float m23,
                                      float w[4]) {
    w[0] =  (y[1]*m23 - y[2]*m13 + y[3]*m12);
    w[1] = -(y[0]*m23 - y[2]*m03 + y[3]*m02);
    w[2] =  (y[0]*m13 - y[1]*m03 + y[3]*m01);
    w[3] = -(y[0]*m12 - y[1]*m02 + y[2]*m01);
}

// ---- per-element solve: char-poly + Newton-8 + adjugate-sum eigvec ----
__device__ __forceinline__ float solve_elem(const float a[10], float4 qt) {
    float m00 = -a[0], m01 = -a[1], m02 = -a[2], m03 = -a[3];
    float m11 = -a[4], m12 = -a[5], m13 = -a[6];
    float m22 = -a[7], m23 = -a[8], m33 = -a[9];

    float e1 = m00 + m11 + m22 + m33;
    float e2 = m00*m11 - m01*m01 + m00*m22 - m02*m02 + m00*m33 - m03*m03
             + m11*m22 - m12*m12 + m11*m33 - m13*m13 + m22*m33 - m23*m23;
    float e3 = det3s(m11, m12, m13, m22, m23, m33)
             + det3s(m00, m02, m03, m22, m23, m33)
             + det3s(m00, m01, m03, m11, m13, m33)
             + det3s(m00, m01, m02, m11, m12, m22);
    // e4 = det A via one generalized cross (rows 1,2,3 dotted with row 0)
    float s01 = m11*m23 - m12*m13;   // minors of rows (2,3) of A... (reused style)
    // direct: cross4(r1,r2,r3) expansion
    {
    }
    float r1v0 = m01, r1v1 = m11, r1v2 = m12, r1v3 = m13;
    float r2v0 = m02, r2v1 = m12, r2v2 = m22, r2v3 = m23;
    float r3v0 = m03, r3v1 = m13, r3v2 = m23, r3v3 = m33;
    float x01 = r2v0*r3v1 - r2v1*r3v0;
    float x02 = r2v0*r3v2 - r2v2*r3v0;
    float x03 = r2v0*r3v3 - r2v3*r3v0;
    float x12 = r2v1*r3v2 - r2v2*r3v1;
    float x13 = r2v1*r3v3 - r2v3*r3v1;
    float x23 = r2v2*r3v3 - r2v3*r3v2;
    float cw0 =  (r1v1*x23 - r1v2*x13 + r1v3*x12);
    float cw1 = -(r1v0*x23 - r1v2*x03 + r1v3*x02);
    float cw2 =  (r1v0*x13 - r1v1*x03 + r1v3*x01);
    float cw3 = -(r1v0*x12 - r1v1*x02 + r1v2*x01);
    float e4 = m00*cw0 + m01*cw1 + m02*cw2 + m03*cw3;
    (void)s01;

    float s0 = fabsf(m01) + fabsf(m02) + fabsf(m03);
    float s1 = fabsf(m01) + fabsf(m12) + fabsf(m13);
    float s2 = fabsf(m02) + fabsf(m12) + fabsf(m23);
    float s3 = fabsf(m03) + fabsf(m13) + fabsf(m23);
    float lo = fminf(fminf(m00 - s0, m11 - s1), fminf(m22 - s2, m33 - s3)) - 1e-3f;
    float hi = fminf(fminf(m00, m11), fminf(m22, m33));
    float lam = lo;
    #pragma unroll
    for (int it = 0; it < 8; ++it) {
        float p  = (((lam - e1)*lam + e2)*lam - e3)*lam + e4;
        float dp = ((4.f*lam - 3.f*e1)*lam + 2.f*e2)*lam - e3;
        dp = fminf(dp, -1e-12f);
        lam = lam - p * __builtin_amdgcn_rcpf(dp);
        lam = fminf(fmaxf(lam, lo), hi);
    }

    // M = A - lam I rows
    float R0[4] = {m00 - lam, m01, m02, m03};
    float R1[4] = {m01, m11 - lam, m12, m13};
    float R2[4] = {m02, m12, m22 - lam, m23};
    float R3[4] = {m03, m13, m23, m33 - lam};

    // w = adj(M) * ones = comb(R1-R0, minors(R2,R3)) + comb(R3-R2, minors(R0,R1))
    float sm01 = R2[0]*R3[1] - R2[1]*R3[0];
    float sm02 = R2[0]*R3[2] - R2[2]*R3[0];
    float sm03 = R2[0]*R3[3] - R2[3]*R3[0];
    float sm12 = R2[1]*R3[2] - R2[2]*R3[1];
    float sm13 = R2[1]*R3[3] - R2[3]*R3[1];
    float sm23 = R2[2]*R3[3] - R2[3]*R3[2];
    float tm01 = R0[0]*R1[1] - R0[1]*R1[0];
    float tm02 = R0[0]*R1[2] - R0[2]*R1[0];
    float tm03 = R0[0]*R1[3] - R0[3]*R1[0];
    float tm12 = R0[1]*R1[2] - R0[2]*R1[1];
    float tm13 = R0[1]*R1[3] - R0[3]*R1[1];
    float tm23 = R0[2]*R1[3] - R0[3]*R1[2];
    float u[4] = {R1[0]-R0[0], R1[1]-R0[1], R1[2]-R0[2], R1[3]-R0[3]};
    float y[4] = {R3[0]-R2[0], R3[1]-R2[1], R3[2]-R2[2], R3[3]-R2[3]};
    float wa[4], wb[4];
    comb4(u, sm01, sm02, sm03, sm12, sm13, sm23, wa);
    comb4(y, tm01, tm02, tm03, tm12, tm13, tm23, wb);
    float w0 = wa[0] + wb[0], w1 = wa[1] + wb[1];
    float w2 = wa[2] + wb[2], w3 = wa[3] + wb[3];
    float bn = w0*w0 + w1*w1 + w2*w2 + w3*w3;

    float d = w0*qt.x + w1*qt.y + w2*qt.z + w3*qt.w;
    float inv = __builtin_amdgcn_rcpf(fmaxf(bn, 1e-20f));
    float loss = 8.f * (bn - d*d) * inv;
    return fminf(fmaxf(loss, 0.f), 8.f);
}

// DPP wave64 sum step: VALU pipe only. ctrl/mask are compile-time consts.
template <int CTRL, int ROW_MASK>
__device__ __forceinline__ float dpp_add(float v) {
    int t = __builtin_amdgcn_update_dpp(0, __builtin_bit_cast(int, v),
                                        CTRL, ROW_MASK, 0xf, true);
    return v + __builtin_bit_cast(float, t);
}

__device__ __forceinline__ float wave_sum(float v) {
    v = dpp_add<0x111, 0xf>(v);   // row_shr:1
    v = dpp_add<0x112, 0xf>(v);   // row_shr:2
    v = dpp_add<0x114, 0xf>(v);   // row_shr:4
    v = dpp_add<0x118, 0xf>(v);   // row_shr:8
    v = dpp_add<0x142, 0xa>(v);   // row_bcast:15 -> rows 1,3
    v = dpp_add<0x143, 0xc>(v);   // row_bcast:31 -> rows 2,3
    return __builtin_bit_cast(float,
        __builtin_amdgcn_readlane(__builtin_bit_cast(int, v), 63));
}

__global__ __launch_bounds__(TPB) void qcqp_loss_kernel(
    const float* __restrict__ A_vec, const float* __restrict__ q_t,
    float* __restrict__ part, int B, int T)
{
    int t = blockIdx.x * blockDim.x + threadIdx.x;
    int Ptot = B >> 1;                       // whole pairs
    float lsum = 0.f;

    Pair Pd, Nd;
    int curp = t;
    {
        int c = (curp < Ptot) ? curp : 0;
        issue_loads(A_vec + (size_t)c * 20, q_t + (size_t)c * 8, Pd);
    }
    int nxtp = curp;

    #define STEP(K, VMSTR)                                                    \
    {                                                                         \
        if ((K) + 1 < PAIRS) {                                                \
            nxtp = t + ((K) + 1) * T;                                         \
            int nc = (nxtp < Ptot) ? nxtp : 0;                                \
            issue_loads(A_vec + (size_t)nc * 20, q_t + (size_t)nc * 8, Nd);   \
        }                                                                     \
        asm volatile("s_waitcnt vmcnt(" VMSTR ")" ::: "memory");              \
        __builtin_amdgcn_sched_barrier(0);                                    \
        {                                                                     \
            bool ok = (curp < Ptot);                                          \
            float a0[10] = {Pd.f0.x, Pd.f0.y, Pd.f0.z, Pd.f0.w,               \
                            Pd.f1.x, Pd.f1.y, Pd.f1.z, Pd.f1.w,               \
                            Pd.f2.x, Pd.f2.y};                                \
            float a1[10] = {Pd.f2.z, Pd.f2.w, Pd.f3.x, Pd.f3.y,               \
                            Pd.f3.z, Pd.f3.w, Pd.f4.x, Pd.f4.y,               \
                            Pd.f4.z, Pd.f4.w};                                \
            float4 qt0 = make_float4(Pd.q0.x, Pd.q0.y, Pd.q0.z, Pd.q0.w);     \
            float4 qt1 = make_float4(Pd.q1.x, Pd.q1.y, Pd.q1.z, Pd.q1.w);     \
            float L0 = solve_elem(a0, qt0);                                   \
            float L1 = solve_elem(a1, qt1);                                   \
            lsum += ok ? (L0 + L1) : 0.f;                                     \
        }                                                                     \
        Pd = Nd; curp = nxtp;                                                 \
    }

    STEP(0, "7")
    STEP(1, "0")
    #undef STEP

    float wsum = wave_sum(lsum);

    __shared__ float sm[TPB / 64];
    int lane = threadIdx.x & 63, wid = threadIdx.x >> 6;
    if (lane == 0) sm[wid] = wsum;
    __syncthreads();
    if (threadIdx.x == 0)
        part[blockIdx.x] = sm[0] + sm[1] + sm[2] + sm[3];   // plain store
}

__global__ __launch_bounds__(TPB) void qcqp_reduce_kernel(
    const float* __restrict__ part, const float* __restrict__ A_vec,
    const float* __restrict__ q_t, float* __restrict__ out,
    int nparts, int B)
{
    float s = 0.f;
    for (int i = threadIdx.x; i < nparts; i += TPB)
        s += part[i];
    float wsum = wave_sum(s);

    __shared__ float sm[TPB / 64];
    int lane = threadIdx.x & 63, wid = threadIdx.x >> 6;
    if (lane == 0) sm[wid] = wsum;
    __syncthreads();
    if (threadIdx.x == 0) {
        float total = sm[0] + sm[1] + sm[2] + sm[3];
        if (B & 1) {   // odd-B tail element (not hit for B=2^20)
            const float* av = A_vec + (size_t)(B - 1) * 10;
            float2 v01 = *(const float2*)(av + 0);
            float2 v23 = *(const float2*)(av + 2);
            float2 v45 = *(const float2*)(av + 4);
            float2 v67 = *(const float2*)(av + 6);
            float2 v89 = *(const float2*)(av + 8);
            float a0[10] = {v01.x, v01.y, v23.x, v23.y, v45.x,
                            v45.y, v67.x, v67.y, v89.x, v89.y};
            float4 qt0 = *(const float4*)(q_t + (size_t)(B - 1) * 4);
            total += solve_elem(a0, qt0);
        }
        out[0] = total / (float)B;
    }
}

extern "C" void kernel_launch(void* const* d_in, const int* in_sizes, int n_in,
                              void* d_out, int out_size, void* d_ws, size_t ws_size,
                              hipStream_t stream)
{
    const float* A_vec = (const float*)d_in[0];
    const float* q_t   = (const float*)d_in[1];
    int B = in_sizes[0] / 10;
    float* part = (float*)d_ws;

    int Ptot = B >> 1;
    int nblocks = (Ptot + TPB * PAIRS - 1) / (TPB * PAIRS);
    int T = nblocks * TPB;                  // thread count; pair idx = t + k*T
    qcqp_loss_kernel<<<nblocks, TPB, 0, stream>>>(A_vec, q_t, part, B, T);
    qcqp_reduce_kernel<<<1, TPB, 0, stream>>>(part, A_vec, q_t,
                                              (float*)d_out, nblocks, B);
}